// Round 12
// baseline (213.373 us; speedup 1.0000x reference)
//
#include <hip/hip_runtime.h>
#include <hip/hip_fp16.h>

// Problem constants (fixed by setup_inputs)
#define B_   8
#define H_   512
#define W_   1024
#define FH_  128
#define FW_  256
#define TW   64
#define TH   16
#define HW_  (TW + 2)    // 66
#define HH_  (TH + 2)    // 18
#define NHALO (HH_ * HW_) // 1188
#define FR_  8           // staged flow rows (fallback mode only)
#define FC_  20          // staged flow cols (fallback mode only)
#define NSLOT 256
#define PLANE (H_ * W_)  // 524288 = 2^19

struct alignas(8) H4 { __half2 a; __half2 b; };   // (r,g) (b,pad)

__device__ __forceinline__ float wave_reduce(float v) {
    #pragma unroll
    for (int off = 32; off > 0; off >>= 1) v += __shfl_down(v, off, 64);
    return v;
}

// Packed horizontal 3-col sums: s=(ΣA,ΣB) q=(ΣA²,ΣB²) c=(ΣAB,ΣAB) ctr=center pair.
struct HR { __half2 s, q, c, ctr; };
__device__ __forceinline__ HR hrowp(const __half2* __restrict__ p) {
    const __half2 p0 = p[0], p1 = p[1], p2 = p[2];
    HR r;
    r.s = __hadd2(__hadd2(p0, p1), p2);
    r.q = __hfma2(p2, p2, __hfma2(p1, p1, __hmul2(p0, p0)));
    r.c = __hfma2(p2, __lowhigh2highlow(p2),
          __hfma2(p1, __lowhigh2highlow(p1),
                  __hmul2(p0, __lowhigh2highlow(p0))));
    r.ctr = p1;
    return r;
}

// Streaming prepass: flow upsample (bilinear align-corners) + grid-sample border
// -> materialized warped img2, interleaved half4/px. Pure TLP hides gather latency.
__global__ __launch_bounds__(256)
void warp_img2(const float* __restrict__ flow, const float* __restrict__ img2,
               H4* __restrict__ wp) {
    const int total = B_ * PLANE;
    for (int p = blockIdx.x * 256 + threadIdx.x; p < total; p += gridDim.x * 256) {
        const int b  = p >> 19;
        const int pp = p & (PLANE - 1);
        const int y  = pp >> 10;
        const int x  = pp & (W_ - 1);
        const float* f0  = flow + (size_t)b * 2 * FH_ * FW_;
        const float* f1  = f0 + FH_ * FW_;
        const float* i20 = img2 + (size_t)b * 3 * PLANE;
        const float* i21 = i20 + PLANE;
        const float* i22 = i21 + PLANE;

        // flow bilinear (align_corners)
        const float ycf = y * (127.0f / 511.0f);
        const float xcf = x * (255.0f / 1023.0f);
        const int y0 = (int)ycf, x0 = (int)xcf;
        const int y1i = min(y0 + 1, FH_ - 1);
        const int x1i = min(x0 + 1, FW_ - 1);
        const float wy = ycf - (float)y0, wx = xcf - (float)x0;
        const uint32_t r0 = (uint32_t)y0 * FW_, r1 = (uint32_t)y1i * FW_;
        const float a00 = f0[r0 + x0], a01 = f0[r0 + x1i];
        const float a10 = f0[r1 + x0], a11 = f0[r1 + x1i];
        const float c00 = f1[r0 + x0], c01 = f1[r0 + x1i];
        const float c10 = f1[r1 + x0], c11 = f1[r1 + x1i];
        const float fxt = fmaf(wx, a01 - a00, a00);
        const float fxb = fmaf(wx, a11 - a10, a10);
        const float fx  = fmaf(wy, fxb - fxt, fxt);
        const float fyt = fmaf(wx, c01 - c00, c00);
        const float fyb = fmaf(wx, c11 - c10, c10);
        const float fy  = fmaf(wy, fyb - fyt, fyt);

        // grid_sample border, align_corners: sample at (x + 4fx, y + 4fy)
        const float gxs = fminf(fmaxf(fmaf(4.0f, fx, (float)x), 0.0f), (float)(W_ - 1));
        const float gys = fminf(fmaxf(fmaf(4.0f, fy, (float)y), 0.0f), (float)(H_ - 1));
        const int sx0 = (int)gxs, sy0 = (int)gys;
        const int sx1 = min(sx0 + 1, W_ - 1);
        const int sy1 = min(sy0 + 1, H_ - 1);
        const float swx = gxs - (float)sx0, swy = gys - (float)sy0;
        const uint32_t p00 = (uint32_t)sy0 * W_ + (uint32_t)sx0;
        const uint32_t p01 = (uint32_t)sy0 * W_ + (uint32_t)sx1;
        const uint32_t p10 = (uint32_t)sy1 * W_ + (uint32_t)sx0;
        const uint32_t p11 = (uint32_t)sy1 * W_ + (uint32_t)sx1;

        float v20, v21, v22;
        {
            const float t = fmaf(swx, i20[p01] - i20[p00], i20[p00]);
            const float u = fmaf(swx, i20[p11] - i20[p10], i20[p10]);
            v20 = fmaf(swy, u - t, t);
        }
        {
            const float t = fmaf(swx, i21[p01] - i21[p00], i21[p00]);
            const float u = fmaf(swx, i21[p11] - i21[p10], i21[p10]);
            v21 = fmaf(swy, u - t, t);
        }
        {
            const float t = fmaf(swx, i22[p01] - i22[p00], i22[p00]);
            const float u = fmaf(swx, i22[p11] - i22[p10], i22[p10]);
            v22 = fmaf(swy, u - t, t);
        }
        wp[p] = { __floats2half2_rn(v20, v21), __floats2half2_rn(v22, 0.f) };
    }
}

// Fused stencil: per 64x16 tile, stage (66x18) halo of packed (img1, warped)
// half2 in LDS (MODE 1: coalesced reads of materialized warp; MODE 0 fallback:
// inline gather), rolling packed-half2 3x3 SSIM, masked accumulation.
template <int MODE>
__global__ __launch_bounds__(256, 8)
void fused_main(const float* __restrict__ flow, const float* __restrict__ img1,
                const float* __restrict__ img2, const float* __restrict__ mask,
                const H4* __restrict__ wp, float* __restrict__ accum) {
    // XCD-aware swizzle: 4096 blocks = 8 XCDs x 512; each XCD owns one batch image.
    const int bid = blockIdx.x;
    const int lin = (bid & 7) * 512 + (bid >> 3);
    const int b   = lin >> 9;            // 0..7
    const int rem = lin & 511;
    const int ty0 = (rem >> 4) * TH;     // 32 y-tiles
    const int tx0 = (rem & 15) * TW;     // 16 x-tiles
    const int tid = threadIdx.x;

    __shared__ __half2 sP[3][HH_][HW_];          // packed (img1, warp) tiles

    const float* i10 = img1 + (size_t)b * 3 * PLANE;
    const float* i11 = i10 + PLANE;
    const float* i12 = i11 + PLANE;

    // ---- Mask loads (independent; overlap with staging latency) ----
    const int lx  = tid & 63;            // column 0..63
    const int lyg = tid >> 6;            // row group 0..3
    const int rb  = lyg * 4;
    const float* mb = mask + (size_t)b * PLANE;
    const uint32_t mb0 = (uint32_t)(ty0 + rb) * W_ + (uint32_t)(tx0 + lx);
    float mreg[4];
    #pragma unroll
    for (int k = 0; k < 4; ++k) mreg[k] = mb[mb0 + (uint32_t)k * W_];

    if (MODE == 1) {
        // ---- Stage halo: coalesced img1 + materialized warp reads ----
        const H4* wpb = wp + (size_t)b * PLANE;
        for (int i = tid; i < NHALO; i += 256) {
            const int ly = i / HW_;
            const int lxh = i - ly * HW_;
            const int gy = ty0 + ly - 1;
            const int gx = tx0 + lxh - 1;
            __half2 o0, o1, o2;
            if (gy >= 0 && gy < H_ && gx >= 0 && gx < W_) {
                const uint32_t p = (uint32_t)gy * W_ + (uint32_t)gx;
                const float v10 = i10[p], v11 = i11[p], v12 = i12[p];
                const H4 w = wpb[p];
                o0 = __halves2half2(__float2half_rn(v10), __low2half(w.a));
                o1 = __halves2half2(__float2half_rn(v11), __high2half(w.a));
                o2 = __halves2half2(__float2half_rn(v12), __low2half(w.b));
            } else {
                o0 = __halves2half2(__float2half_rn(0.f), __float2half_rn(0.f));
                o1 = o0; o2 = o0;
            }
            sP[0][ly][lxh] = o0;
            sP[1][ly][lxh] = o1;
            sP[2][ly][lxh] = o2;
        }
    } else {
        // ---- Fallback: flow footprint in LDS + inline planar gather ----
        __shared__ float sF[2][FR_][FC_];
        const float* f0  = flow + (size_t)b * 2 * FH_ * FW_;
        const float* f1  = f0 + FH_ * FW_;
        const float* i20 = img2 + (size_t)b * 3 * PLANE;
        const float* i21 = i20 + PLANE;
        const float* i22 = i21 + PLANE;
        const int fx0s = (tx0 > 0) ? (int)((float)(tx0 - 1) * (255.0f / 1023.0f)) : 0;
        const int fy0s = (ty0 > 0) ? (int)((float)(ty0 - 1) * (127.0f / 511.0f)) : 0;
        for (int i = tid; i < 2 * FR_ * FC_; i += 256) {
            const int ch = i / (FR_ * FC_);
            const int r  = (i - ch * FR_ * FC_) / FC_;
            const int cc = i - ch * FR_ * FC_ - r * FC_;
            const int sy = min(fy0s + r, FH_ - 1);
            const int sx = min(fx0s + cc, FW_ - 1);
            const float* fp = ch ? f1 : f0;
            sF[ch][r][cc] = fp[(uint32_t)sy * FW_ + (uint32_t)sx];
        }
        __syncthreads();
        for (int i = tid; i < NHALO; i += 256) {
            const int ly = i / HW_;
            const int lxh = i - ly * HW_;
            const int gy = ty0 + ly - 1;
            const int gx = tx0 + lxh - 1;
            float v10 = 0.f, v11 = 0.f, v12 = 0.f;
            float v20 = 0.f, v21 = 0.f, v22 = 0.f;
            if (gy >= 0 && gy < H_ && gx >= 0 && gx < W_) {
                const uint32_t p = (uint32_t)gy * W_ + (uint32_t)gx;
                v10 = i10[p]; v11 = i11[p]; v12 = i12[p];
                const float yc = gy * (127.0f / 511.0f);
                const float xc = gx * (255.0f / 1023.0f);
                const int y0 = (int)yc, x0 = (int)xc;
                const float wy = yc - (float)y0, wx = xc - (float)x0;
                const int yr = y0 - fy0s, xr = x0 - fx0s;
                const float a00 = sF[0][yr][xr],     a01 = sF[0][yr][xr + 1];
                const float a10 = sF[0][yr + 1][xr], a11 = sF[0][yr + 1][xr + 1];
                const float c00 = sF[1][yr][xr],     c01 = sF[1][yr][xr + 1];
                const float c10 = sF[1][yr + 1][xr], c11 = sF[1][yr + 1][xr + 1];
                const float fxt = fmaf(wx, a01 - a00, a00);
                const float fxb = fmaf(wx, a11 - a10, a10);
                const float fx  = fmaf(wy, fxb - fxt, fxt);
                const float fyt = fmaf(wx, c01 - c00, c00);
                const float fyb = fmaf(wx, c11 - c10, c10);
                const float fy  = fmaf(wy, fyb - fyt, fyt);
                const float gxs = fminf(fmaxf(fmaf(4.0f, fx, (float)gx), 0.0f), (float)(W_ - 1));
                const float gys = fminf(fmaxf(fmaf(4.0f, fy, (float)gy), 0.0f), (float)(H_ - 1));
                const int sx0 = (int)gxs, sy0 = (int)gys;
                const int sx1 = min(sx0 + 1, W_ - 1);
                const int sy1 = min(sy0 + 1, H_ - 1);
                const float swx = gxs - (float)sx0, swy = gys - (float)sy0;
                const uint32_t p00 = (uint32_t)sy0 * W_ + (uint32_t)sx0;
                const uint32_t p01 = (uint32_t)sy0 * W_ + (uint32_t)sx1;
                const uint32_t p10 = (uint32_t)sy1 * W_ + (uint32_t)sx0;
                const uint32_t p11 = (uint32_t)sy1 * W_ + (uint32_t)sx1;
                {
                    const float t = fmaf(swx, i20[p01] - i20[p00], i20[p00]);
                    const float u = fmaf(swx, i20[p11] - i20[p10], i20[p10]);
                    v20 = fmaf(swy, u - t, t);
                }
                {
                    const float t = fmaf(swx, i21[p01] - i21[p00], i21[p00]);
                    const float u = fmaf(swx, i21[p11] - i21[p10], i21[p10]);
                    v21 = fmaf(swy, u - t, t);
                }
                {
                    const float t = fmaf(swx, i22[p01] - i22[p00], i22[p00]);
                    const float u = fmaf(swx, i22[p11] - i22[p10], i22[p10]);
                    v22 = fmaf(swy, u - t, t);
                }
            }
            sP[0][ly][lxh] = __floats2half2_rn(v10, v20);
            sP[1][ly][lxh] = __floats2half2_rn(v11, v21);
            sP[2][ly][lxh] = __floats2half2_rn(v12, v22);
        }
    }

    __syncthreads();

    // ---- Rolling packed-half2 3x3 SSIM: 1 column x 4 consecutive rows ----
    const float inv9 = 1.0f / 9.0f;
    const float C1 = 0.0001f, C2 = 0.0009f;
    float dist[4] = {0.f, 0.f, 0.f, 0.f};
    float l1s [4] = {0.f, 0.f, 0.f, 0.f};

    #pragma unroll
    for (int c = 0; c < 3; ++c) {
        HR h0 = hrowp(&sP[c][rb + 0][lx]);
        HR h1 = hrowp(&sP[c][rb + 1][lx]);
        #pragma unroll
        for (int k = 0; k < 4; ++k) {
            const HR h2 = hrowp(&sP[c][rb + k + 2][lx]);
            const __half2 S = __hadd2(__hadd2(h0.s, h1.s), h2.s);
            const __half2 Q = __hadd2(__hadd2(h0.q, h1.q), h2.q);
            const __half2 C = __hadd2(__hadd2(h0.c, h1.c), h2.c);
            const float2 Sf = __half22float2(S);
            const float2 Qf = __half22float2(Q);
            const float sAB = __low2float(C);
            const float mx  = Sf.x * inv9, my = Sf.y * inv9;
            const float vx  = fmaf(-mx, mx, Qf.x * inv9);
            const float vy  = fmaf(-my, my, Qf.y * inv9);
            const float vxy = fmaf(-mx, my, sAB * inv9);
            const float numt = (2.f * mx * my + C1) * (2.f * vxy + C2);
            const float dent = fmaf(fmaf(mx, mx, fmaf(my, my, C1)), (vx + vy + C2), 1e-12f);
            const float ssim = numt * __builtin_amdgcn_rcpf(dent);
            dist[k] += fminf(fmaxf((1.0f - ssim) * 0.5f, 0.f), 1.f);
            const float2 ctr = __half22float2(h1.ctr);
            l1s[k] += fabsf(ctr.x - ctr.y);
            h0 = h1; h1 = h2;
        }
    }

    float num_acc = 0.f, den_acc = 0.f;
    #pragma unroll
    for (int k = 0; k < 4; ++k) {
        const float pmv = 0.28333334f * dist[k] + 0.05f * l1s[k];  // 0.85/3, 0.15/3
        const float m   = (mreg[k] > 0.5f) ? 1.f : 0.f;
        num_acc = fmaf(pmv, m, num_acc);
        den_acc += m;
    }

    float num = wave_reduce(num_acc);
    float den = wave_reduce(den_acc);
    __shared__ float rn[4], rd[4];
    const int wid = tid >> 6, lane = tid & 63;
    if (lane == 0) { rn[wid] = num; rd[wid] = den; }
    __syncthreads();
    if (tid == 0) {
        float* slot = accum + (size_t)(bid & (NSLOT - 1)) * 4;
        atomicAdd(&slot[0], rn[0] + rn[1] + rn[2] + rn[3]);
        atomicAdd(&slot[1], rd[0] + rd[1] + rd[2] + rd[3]);
    }
}

// Smoothness loss on raw flow: sum |dx| and |dy| separately (different counts).
__global__ __launch_bounds__(256)
void smooth_kernel(const float* __restrict__ flow, float* __restrict__ accum) {
    const int N = B_ * 2 * FH_ * FW_;
    float dxs = 0.f, dys = 0.f;
    for (int i = blockIdx.x * 256 + threadIdx.x; i < N; i += gridDim.x * 256) {
        const float f = flow[i];
        const int x = i & (FW_ - 1);
        const int y = (i >> 8) & (FH_ - 1);
        if (x < FW_ - 1) dxs += fabsf(f - flow[i + 1]);
        if (y < FH_ - 1) dys += fabsf(f - flow[i + FW_]);
    }
    dxs = wave_reduce(dxs);
    dys = wave_reduce(dys);
    __shared__ float rn[4], rd[4];
    const int wid = threadIdx.x >> 6, lane = threadIdx.x & 63;
    if (lane == 0) { rn[wid] = dxs; rd[wid] = dys; }
    __syncthreads();
    if (threadIdx.x == 0) {
        float* slot = accum + (size_t)blockIdx.x * 4;
        atomicAdd(&slot[2], rn[0] + rn[1] + rn[2] + rn[3]);
        atomicAdd(&slot[3], rd[0] + rd[1] + rd[2] + rd[3]);
    }
}

// Reduce the 256 accumulator slots and emit the 3 outputs.
__global__ __launch_bounds__(256)
void finalize_kernel(const float* __restrict__ accum, float* __restrict__ out) {
    const int t = threadIdx.x;
    float num = accum[t * 4 + 0];
    float den = accum[t * 4 + 1];
    float dxs = accum[t * 4 + 2];
    float dys = accum[t * 4 + 3];
    num = wave_reduce(num); den = wave_reduce(den);
    dxs = wave_reduce(dxs); dys = wave_reduce(dys);
    __shared__ float r[4][4];
    const int wid = t >> 6, lane = t & 63;
    if (lane == 0) { r[wid][0] = num; r[wid][1] = den; r[wid][2] = dxs; r[wid][3] = dys; }
    __syncthreads();
    if (t == 0) {
        const float tn = r[0][0] + r[1][0] + r[2][0] + r[3][0];
        const float td = r[0][1] + r[1][1] + r[2][1] + r[3][1];
        const float tx = r[0][2] + r[1][2] + r[2][2] + r[3][2];
        const float ty = r[0][3] + r[1][3] + r[2][3] + r[3][3];
        const float photo   = tn / fmaxf(td, 1.0f);
        const float mean_dx = tx / (float)(B_ * 2 * FH_ * (FW_ - 1));
        const float mean_dy = ty / (float)(B_ * 2 * (FH_ - 1) * FW_);
        const float smooth  = mean_dx + mean_dy;
        out[0] = photo + 0.1f * smooth;   // total
        out[1] = photo;
        out[2] = smooth;
    }
}

extern "C" void kernel_launch(void* const* d_in, const int* in_sizes, int n_in,
                              void* d_out, int out_size, void* d_ws, size_t ws_size,
                              hipStream_t stream) {
    const float* flow = (const float*)d_in[0];
    const float* img1 = (const float*)d_in[1];
    const float* img2 = (const float*)d_in[2];
    const float* mask = (const float*)d_in[3];
    float* out   = (float*)d_out;
    float* accum = (float*)d_ws;                      // NSLOT x [num, den, dx, dy]
    H4*    wp    = (H4*)((char*)d_ws + 4096);         // materialized warped img2

    const size_t need = 4096 + sizeof(H4) * (size_t)B_ * PLANE;  // ~33.6 MB
    const bool mat = ws_size >= need;

    hipMemsetAsync(accum, 0, NSLOT * 4 * sizeof(float), stream);
    smooth_kernel<<<NSLOT, 256, 0, stream>>>(flow, accum);
    const int grid = (W_ / TW) * (H_ / TH) * B_;
    if (mat) {
        warp_img2<<<4096, 256, 0, stream>>>(flow, img2, wp);
        fused_main<1><<<grid, 256, 0, stream>>>(flow, img1, img2, mask, wp, accum);
    } else {
        fused_main<0><<<grid, 256, 0, stream>>>(flow, img1, img2, mask, wp, accum);
    }
    finalize_kernel<<<1, 256, 0, stream>>>(accum, out);
}